// Round 2
// baseline (788.221 us; speedup 1.0000x reference)
//
#include <hip/hip_runtime.h>

#define NN 50000
#define EE 800000

using bf16x8 = __attribute__((ext_vector_type(8))) short;
using f32x4  = __attribute__((ext_vector_type(4))) float;
using u16x8  = __attribute__((ext_vector_type(8))) unsigned short;

__device__ __forceinline__ float b2f(unsigned short u) {
    return __uint_as_float(((unsigned)u) << 16);
}
__device__ __forceinline__ unsigned short f2b(float f) {
    unsigned u = __float_as_uint(f);
    u += 0x7FFF + ((u >> 16) & 1);   // round-to-nearest-even
    return (unsigned short)(u >> 16);
}

// ---------------------------------------------------------------------------
// prep: W_q|W_k|W_v|W_skip (fp32) -> Wt[512][128] bf16 (Wt[n][k] = W[k][n]),
//       W_e (fp32) -> Wet[128][96] bf16, and clear deg[]
// ---------------------------------------------------------------------------
__global__ void prep_kernel(const float* __restrict__ Wq,
                            const float* __restrict__ Wk,
                            const float* __restrict__ Wv,
                            const float* __restrict__ Ws,
                            const float* __restrict__ We,
                            unsigned short* __restrict__ Wt,
                            unsigned short* __restrict__ Wet,
                            int* __restrict__ deg) {
    int i = blockIdx.x * 256 + threadIdx.x;
    if (i < 512 * 128) {
        int n = i >> 7, k = i & 127;
        const float* W = (n < 128) ? Wq : (n < 256) ? Wk : (n < 384) ? Wv : Ws;
        Wt[i] = f2b(W[k * 128 + (n & 127)]);
    } else if (i < 512 * 128 + 128 * 96) {
        int j = i - 512 * 128;
        int n = j / 96, k = j - n * 96;
        Wet[j] = f2b(We[k * 128 + n]);
    }
    if (i < NN) deg[i] = 0;
}

// ---------------------------------------------------------------------------
// node projections: X[N,128]fp32 x Wt[512,128]bf16 -> Q,K,V,Skip (bf16)
// block = 256 thr (4 waves), tile 64(M) x 64(N), full K=128 staged in LDS
// ---------------------------------------------------------------------------
__global__ __launch_bounds__(256) void node_gemm(
        const float* __restrict__ X, const unsigned short* __restrict__ Wt,
        const float* __restrict__ bq, const float* __restrict__ bk,
        const float* __restrict__ bv, const float* __restrict__ bs,
        unsigned short* __restrict__ Qb, unsigned short* __restrict__ Kb,
        unsigned short* __restrict__ Vb, unsigned short* __restrict__ Sb) {
    __shared__ unsigned short Al[64][136];   // pitch 136: 2-way bank aliasing (free)
    __shared__ unsigned short Bl[64][136];
    const int tid = threadIdx.x;
    const int m0 = blockIdx.x * 64;
    const int n0 = blockIdx.y * 64;
    {
        int row = tid >> 2, seg = tid & 3;           // 32 elements per thread
        int gr = m0 + row;
        float xv[32];
#pragma unroll
        for (int i = 0; i < 32; i++) xv[i] = 0.f;
        if (gr < NN) {
            const float4* s = (const float4*)(X + (size_t)gr * 128 + seg * 32);
#pragma unroll
            for (int i = 0; i < 8; i++) *(float4*)&xv[i * 4] = s[i];
        }
#pragma unroll
        for (int c = 0; c < 4; c++) {
            u16x8 h;
#pragma unroll
            for (int j = 0; j < 8; j++) h[j] = f2b(xv[c * 8 + j]);
            *(u16x8*)&Al[row][seg * 32 + c * 8] = h;
        }
        const uint4* sb = (const uint4*)(Wt + (size_t)(n0 + row) * 128 + seg * 32);
        uint4 b0 = sb[0], b1 = sb[1], b2 = sb[2], b3 = sb[3];
        uint4* db = (uint4*)&Bl[row][seg * 32];
        db[0] = b0; db[1] = b1; db[2] = b2; db[3] = b3;
    }
    __syncthreads();
    const int wave = tid >> 6, lane = tid & 63, quad = lane >> 4, l16 = lane & 15;
    f32x4 acc[4] = {{0.f,0.f,0.f,0.f},{0.f,0.f,0.f,0.f},{0.f,0.f,0.f,0.f},{0.f,0.f,0.f,0.f}};
#pragma unroll
    for (int kk = 0; kk < 4; kk++) {
        bf16x8 af = *(const bf16x8*)&Al[wave * 16 + l16][kk * 32 + quad * 8];
#pragma unroll
        for (int nf = 0; nf < 4; nf++) {
            bf16x8 bg = *(const bf16x8*)&Bl[nf * 16 + l16][kk * 32 + quad * 8];
            acc[nf] = __builtin_amdgcn_mfma_f32_16x16x32_bf16(af, bg, acc[nf], 0, 0, 0);
        }
    }
    const int sel = n0 >> 7;
    const float* bias    = sel == 0 ? bq : sel == 1 ? bk : sel == 2 ? bv : bs;
    unsigned short* outp = sel == 0 ? Qb : sel == 1 ? Kb : sel == 2 ? Vb : Sb;
#pragma unroll
    for (int nf = 0; nf < 4; nf++) {
        int col = (n0 & 127) + nf * 16 + l16;
        float bvl = bias[col];
#pragma unroll
        for (int r = 0; r < 4; r++) {
            int row = m0 + wave * 16 + quad * 4 + r;   // C/D: row = quad*4+reg
            if (row < NN) outp[(size_t)row * 128 + col] = f2b(acc[nf][r] + bvl);
        }
    }
}

// ---------------------------------------------------------------------------
// CSR build: deg histogram -> exclusive scan -> scatter edge ids
// ---------------------------------------------------------------------------
__global__ void deg_kernel(const int* __restrict__ ei, int* __restrict__ deg) {
    int e = blockIdx.x * 256 + threadIdx.x;
    if (e < EE) atomicAdd(&deg[ei[EE + e]], 1);
}

__global__ __launch_bounds__(1024) void scan_kernel(const int* __restrict__ deg,
                                                    int* __restrict__ off,
                                                    int* __restrict__ cur) {
    __shared__ int sums[1024];
    int tid = threadIdx.x;
    const int CH = (NN + 1023) / 1024;   // 49
    int base = tid * CH;
    int s = 0;
    for (int i = 0; i < CH; i++) { int idx = base + i; if (idx < NN) s += deg[idx]; }
    sums[tid] = s;
    __syncthreads();
    for (int d = 1; d < 1024; d <<= 1) {
        int v = (tid >= d) ? sums[tid - d] : 0;
        __syncthreads();
        if (tid >= d) sums[tid] += v;
        __syncthreads();
    }
    int run = sums[tid] - s;   // exclusive prefix of this chunk
    for (int i = 0; i < CH; i++) {
        int idx = base + i;
        if (idx < NN) { off[idx] = run; cur[idx] = run; run += deg[idx]; }
    }
    if (tid == 1023) off[NN] = sums[1023];
}

__global__ void scatter_kernel(const int* __restrict__ ei, int* __restrict__ cur,
                               int* __restrict__ elist) {
    int e = blockIdx.x * 256 + threadIdx.x;
    if (e < EE) {
        int d = ei[EE + e];
        int p = atomicAdd(&cur[d], 1);
        elist[p] = e;
    }
}

// ---------------------------------------------------------------------------
// fused per-node attention: one wave per node; per 16-edge tile:
//   build edge_attr [16,96] bf16 in LDS (cos time-enc + msg fp32->bf16)
//   -> MFMA vs W_e^T (LDS) -> alpha = q.(k+e)/8 (quad shuffles, fp32)
//   -> exp (unnormalized, safe range) -> accumulate ex*(v+e), denom in regs
//   -> out = num/den + skip   (fp32 out)
// ---------------------------------------------------------------------------
__global__ __launch_bounds__(256) void attn_kernel(
        const unsigned short* __restrict__ Qb, const unsigned short* __restrict__ Kb,
        const unsigned short* __restrict__ Vb, const unsigned short* __restrict__ Sb,
        const unsigned short* __restrict__ Wet, const float* __restrict__ be,
        const float* __restrict__ wt,  const float* __restrict__ bt,
        const float* __restrict__ lu,  const float* __restrict__ tt,
        const float* __restrict__ msg, const int* __restrict__ ei,
        const int* __restrict__ off, const int* __restrict__ elist,
        float* __restrict__ outp) {
    __shared__ unsigned short Wl[128][104];      // W_e^T, pitch 104
    __shared__ unsigned short ea[4][16][104];    // per-wave edge_attr tile
    __shared__ int esrc[4][16];
    const int tid = threadIdx.x;
    {   // stage W_e^T: 2 threads per row, 48 shorts each
        int r = tid >> 1, half = tid & 1;
        const uint4* s = (const uint4*)(Wet + r * 96 + half * 48);
        uint4* d = (uint4*)&Wl[r][half * 48];
#pragma unroll
        for (int i = 0; i < 6; i++) d[i] = s[i];
    }
    __syncthreads();
    const int wave = tid >> 6, lane = tid & 63, quad = lane >> 4, l16 = lane & 15;
    const int er = lane >> 2, part = lane & 3;
    float q_be[8], wtv[8], btv[8];
#pragma unroll
    for (int nf = 0; nf < 8; nf++) q_be[nf] = be[l16 + nf * 16];
#pragma unroll
    for (int j = 0; j < 8; j++) { wtv[j] = wt[part * 8 + j]; btv[j] = bt[part * 8 + j]; }

    const int node = blockIdx.x * 4 + wave;
    if (node >= NN) return;
    const int e0 = off[node];
    const int dg = off[node + 1] - e0;
    float qv[8];
#pragma unroll
    for (int nf = 0; nf < 8; nf++) qv[nf] = b2f(Qb[(size_t)node * 128 + l16 + nf * 16]);
    float accv[8] = {0.f,0.f,0.f,0.f,0.f,0.f,0.f,0.f};
    float l0 = 0.f, l1 = 0.f;

    for (int tb = 0; tb < dg; tb += 16) {
        int cnt = dg - tb; if (cnt > 16) cnt = 16;
        // prior tile's LDS reads retire before overwrite (per-wave ordering)
        __asm__ volatile("s_waitcnt lgkmcnt(0)" ::: "memory");
        int eid = -1, sid = 0;
        if (er < cnt) { eid = elist[e0 + tb + er]; sid = ei[eid]; }   // ei row0 = src
        if (part == 0) esrc[wave][er] = sid;
        // msg (fp32) -> cols 32..95  (4 lanes x 16 elements per edge)
        float mv[16];
#pragma unroll
        for (int i = 0; i < 16; i++) mv[i] = 0.f;
        if (eid >= 0) {
            const float4* mp = (const float4*)(msg + (size_t)eid * 64 + part * 16);
#pragma unroll
            for (int i = 0; i < 4; i++) *(float4*)&mv[i * 4] = mp[i];
        }
#pragma unroll
        for (int c = 0; c < 2; c++) {
            u16x8 h;
#pragma unroll
            for (int j = 0; j < 8; j++) h[j] = f2b(mv[c * 8 + j]);
            *(u16x8*)&ea[wave][er][32 + part * 16 + c * 8] = h;
        }
        // time encoding -> cols 0..31
        u16x8 tv = {0,0,0,0,0,0,0,0};
        if (eid >= 0) {
            float rel = lu[sid] - tt[eid];
#pragma unroll
            for (int j = 0; j < 8; j++) tv[j] = f2b(__cosf(rel * wtv[j] + btv[j]));
        }
        *(u16x8*)&ea[wave][er][part * 8] = tv;
        __asm__ volatile("s_waitcnt lgkmcnt(0)" ::: "memory");

        f32x4 acc8[8] = {{0.f,0.f,0.f,0.f},{0.f,0.f,0.f,0.f},{0.f,0.f,0.f,0.f},{0.f,0.f,0.f,0.f},
                         {0.f,0.f,0.f,0.f},{0.f,0.f,0.f,0.f},{0.f,0.f,0.f,0.f},{0.f,0.f,0.f,0.f}};
#pragma unroll
        for (int kk = 0; kk < 3; kk++) {
            bf16x8 af = *(const bf16x8*)&ea[wave][l16][kk * 32 + quad * 8];
#pragma unroll
            for (int nf = 0; nf < 8; nf++) {
                bf16x8 bg = *(const bf16x8*)&Wl[l16 + nf * 16][kk * 32 + quad * 8];
                acc8[nf] = __builtin_amdgcn_mfma_f32_16x16x32_bf16(af, bg, acc8[nf], 0, 0, 0);
            }
        }
        // e sits in C/D layout: edge = quad*4+r, col = l16 + nf*16
#pragma unroll
        for (int r = 0; r < 4; r++) {
            int slot = quad * 4 + r;
            int ssid = esrc[wave][slot];
            const unsigned short* kp = Kb + (size_t)ssid * 128;
            float p0 = 0.f, p1 = 0.f;
#pragma unroll
            for (int nf = 0; nf < 8; nf++) {
                float ev = acc8[nf][r] + q_be[nf];
                float kj = b2f(kp[l16 + nf * 16]) + ev;
                if (nf < 4) p0 += qv[nf] * kj; else p1 += qv[nf] * kj;
            }
#pragma unroll
            for (int m = 1; m < 16; m <<= 1) {        // reduce across quad's 16 lanes
                p0 += __shfl_xor(p0, m, 64);
                p1 += __shfl_xor(p1, m, 64);
            }
            bool valid = slot < cnt;
            float ex0 = valid ? __expf(p0 * 0.125f) : 0.f;
            float ex1 = valid ? __expf(p1 * 0.125f) : 0.f;
            l0 += ex0; l1 += ex1;
            const unsigned short* vp = Vb + (size_t)ssid * 128;
#pragma unroll
            for (int nf = 0; nf < 8; nf++) {
                float ev = acc8[nf][r] + q_be[nf];
                float vv = b2f(vp[l16 + nf * 16]) + ev;
                accv[nf] += (nf < 4 ? ex0 : ex1) * vv;
            }
        }
    }
    // combine the 4 quads (each quad summed its own 4 edges per tile)
#pragma unroll
    for (int m = 16; m < 64; m <<= 1) {
        l0 += __shfl_xor(l0, m, 64);
        l1 += __shfl_xor(l1, m, 64);
#pragma unroll
        for (int nf = 0; nf < 8; nf++) accv[nf] += __shfl_xor(accv[nf], m, 64);
    }
    float inv0 = 1.f / (l0 + 1e-16f), inv1 = 1.f / (l1 + 1e-16f);
#pragma unroll
    for (int j = 0; j < 2; j++) {
        int nf = quad * 2 + j;
        int col = l16 + nf * 16;
        float o = accv[nf] * (nf < 4 ? inv0 : inv1) + b2f(Sb[(size_t)node * 128 + col]);
        outp[(size_t)node * 128 + col] = o;
    }
}

// ---------------------------------------------------------------------------
extern "C" void kernel_launch(void* const* d_in, const int* in_sizes, int n_in,
                              void* d_out, int out_size, void* d_ws, size_t ws_size,
                              hipStream_t stream) {
    (void)in_sizes; (void)n_in; (void)out_size; (void)ws_size;
    const float* x   = (const float*)d_in[0];
    const float* lu  = (const float*)d_in[1];
    const float* tt  = (const float*)d_in[2];
    const float* msg = (const float*)d_in[3];
    const int*   ei  = (const int*)d_in[4];
    const float* wt  = (const float*)d_in[5];
    const float* btm = (const float*)d_in[6];
    const float* Wq  = (const float*)d_in[7];
    const float* bq  = (const float*)d_in[8];
    const float* Wk  = (const float*)d_in[9];
    const float* bk  = (const float*)d_in[10];
    const float* Wv  = (const float*)d_in[11];
    const float* bv  = (const float*)d_in[12];
    const float* We  = (const float*)d_in[13];
    const float* be  = (const float*)d_in[14];
    const float* Ws  = (const float*)d_in[15];
    const float* bs  = (const float*)d_in[16];

    char* p = (char*)d_ws;
    auto alloc = [&](size_t bytes) -> char* {
        char* r = p; p += (bytes + 255) & ~(size_t)255; return r;
    };
    unsigned short* Qb   = (unsigned short*)alloc((size_t)NN * 128 * 2);
    unsigned short* Kb   = (unsigned short*)alloc((size_t)NN * 128 * 2);
    unsigned short* Vb   = (unsigned short*)alloc((size_t)NN * 128 * 2);
    unsigned short* Sb   = (unsigned short*)alloc((size_t)NN * 128 * 2);
    unsigned short* Wt   = (unsigned short*)alloc(512 * 128 * 2);
    unsigned short* Wet  = (unsigned short*)alloc(128 * 96 * 2);
    int* deg   = (int*)alloc(NN * 4);
    int* cur   = (int*)alloc(NN * 4);
    int* off   = (int*)alloc((NN + 1) * 4);
    int* elist = (int*)alloc((size_t)EE * 4);

    hipLaunchKernelGGL(prep_kernel, dim3(304), dim3(256), 0, stream,
                       Wq, Wk, Wv, Ws, We, Wt, Wet, deg);
    hipLaunchKernelGGL(node_gemm, dim3(782, 8), dim3(256), 0, stream,
                       x, Wt, bq, bk, bv, bs, Qb, Kb, Vb, Sb);
    hipLaunchKernelGGL(deg_kernel, dim3((EE + 255) / 256), dim3(256), 0, stream, ei, deg);
    hipLaunchKernelGGL(scan_kernel, dim3(1), dim3(1024), 0, stream, deg, off, cur);
    hipLaunchKernelGGL(scatter_kernel, dim3((EE + 255) / 256), dim3(256), 0, stream,
                       ei, cur, elist);
    hipLaunchKernelGGL(attn_kernel, dim3((NN + 3) / 4), dim3(256), 0, stream,
                       Qb, Kb, Vb, Sb, Wet, be, wt, btm, lu, tt, msg, ei, off, elist,
                       (float*)d_out);
}

// Round 3
// 630.136 us; speedup vs baseline: 1.2509x; 1.2509x over previous
//
#include <hip/hip_runtime.h>

#define NN 50000
#define EE 800000
#define ATTN_BLOCKS 1024
#define ATTN_WAVES (ATTN_BLOCKS * 4)

using bf16x8 = __attribute__((ext_vector_type(8))) short;
using f32x4  = __attribute__((ext_vector_type(4))) float;
using u16x8  = __attribute__((ext_vector_type(8))) unsigned short;

__device__ __forceinline__ float b2f(unsigned short u) {
    return __uint_as_float(((unsigned)u) << 16);
}
__device__ __forceinline__ unsigned short f2b(float f) {
    unsigned u = __float_as_uint(f);
    u += 0x7FFF + ((u >> 16) & 1);   // round-to-nearest-even
    return (unsigned short)(u >> 16);
}

// ---------------------------------------------------------------------------
// prep: W_q|W_k|W_v|W_skip (fp32) -> Wt[512][128] bf16 (Wt[n][k] = W[k][n]),
//       W_e (fp32) -> Wet[128][96] bf16, and clear deg[]
// ---------------------------------------------------------------------------
__global__ void prep_kernel(const float* __restrict__ Wq,
                            const float* __restrict__ Wk,
                            const float* __restrict__ Wv,
                            const float* __restrict__ Ws,
                            const float* __restrict__ We,
                            unsigned short* __restrict__ Wt,
                            unsigned short* __restrict__ Wet,
                            int* __restrict__ deg) {
    int i = blockIdx.x * 256 + threadIdx.x;
    if (i < 512 * 128) {
        int n = i >> 7, k = i & 127;
        const float* W = (n < 128) ? Wq : (n < 256) ? Wk : (n < 384) ? Wv : Ws;
        Wt[i] = f2b(W[k * 128 + (n & 127)]);
    } else if (i < 512 * 128 + 128 * 96) {
        int j = i - 512 * 128;
        int n = j / 96, k = j - n * 96;
        Wet[j] = f2b(We[k * 128 + n]);
    }
    if (i < NN) deg[i] = 0;
}

// ---------------------------------------------------------------------------
// node projections: X[N,128]fp32 x Wt[512,128]bf16 -> Q,K,V,Skip (bf16)
// block = 256 thr (4 waves), M-tile 64; X staged ONCE, loop over 8 N-tiles
// ---------------------------------------------------------------------------
__global__ __launch_bounds__(256) void node_gemm(
        const float* __restrict__ X, const unsigned short* __restrict__ Wt,
        const float* __restrict__ bq, const float* __restrict__ bk,
        const float* __restrict__ bv, const float* __restrict__ bs,
        unsigned short* __restrict__ Qb, unsigned short* __restrict__ Kb,
        unsigned short* __restrict__ Vb, unsigned short* __restrict__ Sb) {
    __shared__ unsigned short Al[64][136];   // pitch 136: 2-way bank aliasing (free)
    __shared__ unsigned short Bl[64][136];
    const int tid = threadIdx.x;
    const int m0 = blockIdx.x * 64;
    const int row = tid >> 2, seg = tid & 3;
    {
        int gr = m0 + row;
        float xv[32];
#pragma unroll
        for (int i = 0; i < 32; i++) xv[i] = 0.f;
        if (gr < NN) {
            const float4* s = (const float4*)(X + (size_t)gr * 128 + seg * 32);
#pragma unroll
            for (int i = 0; i < 8; i++) *(float4*)&xv[i * 4] = s[i];
        }
#pragma unroll
        for (int c = 0; c < 4; c++) {
            u16x8 h;
#pragma unroll
            for (int j = 0; j < 8; j++) h[j] = f2b(xv[c * 8 + j]);
            *(u16x8*)&Al[row][seg * 32 + c * 8] = h;
        }
    }
    const int wave = tid >> 6, lane = tid & 63, quad = lane >> 4, l16 = lane & 15;
    for (int n0t = 0; n0t < 8; n0t++) {
        __syncthreads();   // prior MFMA LDS reads done (and Al staged, iter 0)
        {
            const uint4* sb = (const uint4*)(Wt + (size_t)(n0t * 64 + row) * 128 + seg * 32);
            uint4 b0 = sb[0], b1 = sb[1], b2 = sb[2], b3 = sb[3];
            uint4* db = (uint4*)&Bl[row][seg * 32];
            db[0] = b0; db[1] = b1; db[2] = b2; db[3] = b3;
        }
        __syncthreads();
        f32x4 acc[4] = {{0.f,0.f,0.f,0.f},{0.f,0.f,0.f,0.f},{0.f,0.f,0.f,0.f},{0.f,0.f,0.f,0.f}};
#pragma unroll
        for (int kk = 0; kk < 4; kk++) {
            bf16x8 af = *(const bf16x8*)&Al[wave * 16 + l16][kk * 32 + quad * 8];
#pragma unroll
            for (int nf = 0; nf < 4; nf++) {
                bf16x8 bg = *(const bf16x8*)&Bl[nf * 16 + l16][kk * 32 + quad * 8];
                acc[nf] = __builtin_amdgcn_mfma_f32_16x16x32_bf16(af, bg, acc[nf], 0, 0, 0);
            }
        }
        const int sel = n0t >> 1;
        const float* bias    = sel == 0 ? bq : sel == 1 ? bk : sel == 2 ? bv : bs;
        unsigned short* outp = sel == 0 ? Qb : sel == 1 ? Kb : sel == 2 ? Vb : Sb;
#pragma unroll
        for (int nf = 0; nf < 4; nf++) {
            int col = (n0t & 1) * 64 + nf * 16 + l16;
            float bvl = bias[col];
#pragma unroll
            for (int r = 0; r < 4; r++) {
                int orow = m0 + wave * 16 + quad * 4 + r;   // C/D: row = quad*4+reg
                if (orow < NN) outp[(size_t)orow * 128 + col] = f2b(acc[nf][r] + bvl);
            }
        }
    }
}

// ---------------------------------------------------------------------------
// CSR build: deg histogram -> hierarchical exclusive scan -> scatter edge ids
// ---------------------------------------------------------------------------
__global__ void deg_kernel(const int* __restrict__ ei, int* __restrict__ deg) {
    int e = blockIdx.x * 256 + threadIdx.x;
    if (e < EE) atomicAdd(&deg[ei[EE + e]], 1);
}

#define SCAN_BLKS 196   // 196*256 = 50176 >= NN

__global__ __launch_bounds__(256) void scan1_kernel(const int* __restrict__ deg,
                                                    int* __restrict__ off,
                                                    int* __restrict__ bsum) {
    __shared__ int sm[256];
    int tid = threadIdx.x;
    int i = blockIdx.x * 256 + tid;
    int v = (i < NN) ? deg[i] : 0;
    sm[tid] = v;
    __syncthreads();
    for (int d = 1; d < 256; d <<= 1) {
        int t = (tid >= d) ? sm[tid - d] : 0;
        __syncthreads();
        sm[tid] += t;
        __syncthreads();
    }
    if (i < NN) off[i] = sm[tid] - v;           // block-local exclusive
    if (tid == 255) bsum[blockIdx.x] = sm[255]; // block total
}

__global__ __launch_bounds__(256) void scan2_kernel(int* __restrict__ bsum,
                                                    int* __restrict__ bpre,
                                                    int* __restrict__ off) {
    __shared__ int sm[256];
    int tid = threadIdx.x;
    int v = (tid < SCAN_BLKS) ? bsum[tid] : 0;
    sm[tid] = v;
    __syncthreads();
    for (int d = 1; d < 256; d <<= 1) {
        int t = (tid >= d) ? sm[tid - d] : 0;
        __syncthreads();
        sm[tid] += t;
        __syncthreads();
    }
    if (tid < SCAN_BLKS) bpre[tid] = sm[tid] - v;
    if (tid == 255) off[NN] = sm[255];          // = EE
}

__global__ __launch_bounds__(256) void scan3_kernel(int* __restrict__ off,
                                                    const int* __restrict__ bpre,
                                                    int* __restrict__ cur) {
    int i = blockIdx.x * 256 + threadIdx.x;
    if (i < NN) {
        int o = off[i] + bpre[blockIdx.x];
        off[i] = o;
        cur[i] = o;
    }
}

__global__ void scatter_kernel(const int* __restrict__ ei, int* __restrict__ cur,
                               int* __restrict__ elist) {
    int e = blockIdx.x * 256 + threadIdx.x;
    if (e < EE) {
        int d = ei[EE + e];
        int p = atomicAdd(&cur[d], 1);
        elist[p] = e;
    }
}

// ---------------------------------------------------------------------------
// fused per-node attention, persistent waves: each wave grid-strides over
// nodes (ATTN_WAVES total waves, ~12 nodes each). Per 16-edge tile:
//   build edge_attr [16,96] bf16 in LDS -> MFMA vs W_e^T (acc init = b_e)
//   -> alpha = q.(k+e)/8 (quad shuffles) -> exp -> accumulate ex*(v+e), denom
//   -> out = num/den + skip   (fp32 out)
// ---------------------------------------------------------------------------
__global__ __launch_bounds__(256) void attn_kernel(
        const unsigned short* __restrict__ Qb, const unsigned short* __restrict__ Kb,
        const unsigned short* __restrict__ Vb, const unsigned short* __restrict__ Sb,
        const unsigned short* __restrict__ Wet, const float* __restrict__ be,
        const float* __restrict__ wt,  const float* __restrict__ bt,
        const float* __restrict__ lu,  const float* __restrict__ tt,
        const float* __restrict__ msg, const int* __restrict__ ei,
        const int* __restrict__ off, const int* __restrict__ elist,
        float* __restrict__ outp) {
    __shared__ unsigned short Wl[128][104];      // W_e^T, pitch 104
    __shared__ unsigned short ea[4][16][104];    // per-wave edge_attr tile
    __shared__ int esrc[4][16];
    const int tid = threadIdx.x;
    {   // stage W_e^T once per block: 2 threads per row, 48 shorts each
        int r = tid >> 1, half = tid & 1;
        const uint4* s = (const uint4*)(Wet + r * 96 + half * 48);
        uint4* d = (uint4*)&Wl[r][half * 48];
#pragma unroll
        for (int i = 0; i < 6; i++) d[i] = s[i];
    }
    __syncthreads();
    const int wave = tid >> 6, lane = tid & 63, quad = lane >> 4, l16 = lane & 15;
    const int er = lane >> 2, part = lane & 3;
    float q_be[8], wtv[8], btv[8];
#pragma unroll
    for (int nf = 0; nf < 8; nf++) q_be[nf] = be[l16 + nf * 16];
#pragma unroll
    for (int j = 0; j < 8; j++) { wtv[j] = wt[part * 8 + j]; btv[j] = bt[part * 8 + j]; }

    const int wid = blockIdx.x * 4 + wave;
    for (int node = wid; node < NN; node += ATTN_WAVES) {
        const int e0 = off[node];
        const int dg = off[node + 1] - e0;
        float qv[8];
#pragma unroll
        for (int nf = 0; nf < 8; nf++) qv[nf] = b2f(Qb[(size_t)node * 128 + l16 + nf * 16]);
        float accv[8] = {0.f,0.f,0.f,0.f,0.f,0.f,0.f,0.f};
        float l0 = 0.f, l1 = 0.f;

        for (int tb = 0; tb < dg; tb += 16) {
            int cnt = dg - tb; if (cnt > 16) cnt = 16;
            // prior tile's LDS reads retire before overwrite (per-wave ordering)
            __asm__ volatile("s_waitcnt lgkmcnt(0)" ::: "memory");
            int eid = -1, sid = 0;
            if (er < cnt) { eid = elist[e0 + tb + er]; sid = ei[eid]; }   // ei row0 = src
            if (part == 0) esrc[wave][er] = sid;
            // msg (fp32) -> cols 32..95  (4 lanes x 16 elements per edge)
            float mv[16];
#pragma unroll
            for (int i = 0; i < 16; i++) mv[i] = 0.f;
            if (eid >= 0) {
                const float4* mp = (const float4*)(msg + (size_t)eid * 64 + part * 16);
#pragma unroll
                for (int i = 0; i < 4; i++) *(float4*)&mv[i * 4] = mp[i];
            }
#pragma unroll
            for (int c = 0; c < 2; c++) {
                u16x8 h;
#pragma unroll
                for (int j = 0; j < 8; j++) h[j] = f2b(mv[c * 8 + j]);
                *(u16x8*)&ea[wave][er][32 + part * 16 + c * 8] = h;
            }
            // time encoding -> cols 0..31
            u16x8 tv = {0,0,0,0,0,0,0,0};
            if (eid >= 0) {
                float rel = lu[sid] - tt[eid];
#pragma unroll
                for (int j = 0; j < 8; j++) tv[j] = f2b(__cosf(rel * wtv[j] + btv[j]));
            }
            *(u16x8*)&ea[wave][er][part * 8] = tv;
            __asm__ volatile("s_waitcnt lgkmcnt(0)" ::: "memory");

            // acc init = b_e  ->  e-projection output includes bias directly
            f32x4 acc8[8];
#pragma unroll
            for (int nf = 0; nf < 8; nf++) {
                float b = q_be[nf];
                acc8[nf] = (f32x4){b, b, b, b};
            }
#pragma unroll
            for (int kk = 0; kk < 3; kk++) {
                bf16x8 af = *(const bf16x8*)&ea[wave][l16][kk * 32 + quad * 8];
#pragma unroll
                for (int nf = 0; nf < 8; nf++) {
                    bf16x8 bg = *(const bf16x8*)&Wl[l16 + nf * 16][kk * 32 + quad * 8];
                    acc8[nf] = __builtin_amdgcn_mfma_f32_16x16x32_bf16(af, bg, acc8[nf], 0, 0, 0);
                }
            }
            // e sits in C/D layout: edge = quad*4+r, col = l16 + nf*16
#pragma unroll
            for (int r = 0; r < 4; r++) {
                int slot = quad * 4 + r;
                int ssid = esrc[wave][slot];
                const unsigned short* kp = Kb + (size_t)ssid * 128;
                float p0 = 0.f, p1 = 0.f;
#pragma unroll
                for (int nf = 0; nf < 8; nf++) {
                    float kj = b2f(kp[l16 + nf * 16]) + acc8[nf][r];
                    if (nf < 4) p0 += qv[nf] * kj; else p1 += qv[nf] * kj;
                }
#pragma unroll
                for (int m = 1; m < 16; m <<= 1) {        // reduce across quad's 16 lanes
                    p0 += __shfl_xor(p0, m, 64);
                    p1 += __shfl_xor(p1, m, 64);
                }
                bool valid = slot < cnt;
                float ex0 = valid ? __expf(p0 * 0.125f) : 0.f;
                float ex1 = valid ? __expf(p1 * 0.125f) : 0.f;
                l0 += ex0; l1 += ex1;
                const unsigned short* vp = Vb + (size_t)ssid * 128;
#pragma unroll
                for (int nf = 0; nf < 8; nf++) {
                    float vv = b2f(vp[l16 + nf * 16]) + acc8[nf][r];
                    accv[nf] += (nf < 4 ? ex0 : ex1) * vv;
                }
            }
        }
        // combine the 4 quads (each quad summed its own 4 edges per tile)
#pragma unroll
        for (int m = 16; m < 64; m <<= 1) {
            l0 += __shfl_xor(l0, m, 64);
            l1 += __shfl_xor(l1, m, 64);
#pragma unroll
            for (int nf = 0; nf < 8; nf++) accv[nf] += __shfl_xor(accv[nf], m, 64);
        }
        float inv0 = 1.f / (l0 + 1e-16f), inv1 = 1.f / (l1 + 1e-16f);
#pragma unroll
        for (int j = 0; j < 2; j++) {
            int nf = quad * 2 + j;
            int col = l16 + nf * 16;
            float o = accv[nf] * (nf < 4 ? inv0 : inv1) + b2f(Sb[(size_t)node * 128 + col]);
            outp[(size_t)node * 128 + col] = o;
        }
    }
}

// ---------------------------------------------------------------------------
extern "C" void kernel_launch(void* const* d_in, const int* in_sizes, int n_in,
                              void* d_out, int out_size, void* d_ws, size_t ws_size,
                              hipStream_t stream) {
    (void)in_sizes; (void)n_in; (void)out_size; (void)ws_size;
    const float* x   = (const float*)d_in[0];
    const float* lu  = (const float*)d_in[1];
    const float* tt  = (const float*)d_in[2];
    const float* msg = (const float*)d_in[3];
    const int*   ei  = (const int*)d_in[4];
    const float* wt  = (const float*)d_in[5];
    const float* btm = (const float*)d_in[6];
    const float* Wq  = (const float*)d_in[7];
    const float* bq  = (const float*)d_in[8];
    const float* Wk  = (const float*)d_in[9];
    const float* bk  = (const float*)d_in[10];
    const float* Wv  = (const float*)d_in[11];
    const float* bv  = (const float*)d_in[12];
    const float* We  = (const float*)d_in[13];
    const float* be  = (const float*)d_in[14];
    const float* Ws  = (const float*)d_in[15];
    const float* bs  = (const float*)d_in[16];

    char* p = (char*)d_ws;
    auto alloc = [&](size_t bytes) -> char* {
        char* r = p; p += (bytes + 255) & ~(size_t)255; return r;
    };
    unsigned short* Qb   = (unsigned short*)alloc((size_t)NN * 128 * 2);
    unsigned short* Kb   = (unsigned short*)alloc((size_t)NN * 128 * 2);
    unsigned short* Vb   = (unsigned short*)alloc((size_t)NN * 128 * 2);
    unsigned short* Sb   = (unsigned short*)alloc((size_t)NN * 128 * 2);
    unsigned short* Wt   = (unsigned short*)alloc(512 * 128 * 2);
    unsigned short* Wet  = (unsigned short*)alloc(128 * 96 * 2);
    int* deg   = (int*)alloc(NN * 4);
    int* cur   = (int*)alloc(NN * 4);
    int* off   = (int*)alloc((NN + 1) * 4);
    int* elist = (int*)alloc((size_t)EE * 4);
    int* bsum  = (int*)alloc(SCAN_BLKS * 4);
    int* bpre  = (int*)alloc(SCAN_BLKS * 4);

    hipLaunchKernelGGL(prep_kernel, dim3(304), dim3(256), 0, stream,
                       Wq, Wk, Wv, Ws, We, Wt, Wet, deg);
    hipLaunchKernelGGL(node_gemm, dim3(782), dim3(256), 0, stream,
                       x, Wt, bq, bk, bv, bs, Qb, Kb, Vb, Sb);
    hipLaunchKernelGGL(deg_kernel, dim3((EE + 255) / 256), dim3(256), 0, stream, ei, deg);
    hipLaunchKernelGGL(scan1_kernel, dim3(SCAN_BLKS), dim3(256), 0, stream, deg, off, bsum);
    hipLaunchKernelGGL(scan2_kernel, dim3(1), dim3(256), 0, stream, bsum, bpre, off);
    hipLaunchKernelGGL(scan3_kernel, dim3(SCAN_BLKS), dim3(256), 0, stream, off, bpre, cur);
    hipLaunchKernelGGL(scatter_kernel, dim3((EE + 255) / 256), dim3(256), 0, stream,
                       ei, cur, elist);
    hipLaunchKernelGGL(attn_kernel, dim3(ATTN_BLOCKS), dim3(256), 0, stream,
                       Qb, Kb, Vb, Sb, Wet, be, wt, btm, lu, tt, msg, ei, off, elist,
                       (float*)d_out);
}